// Round 6
// baseline (131.628 us; speedup 1.0000x reference)
//
#include <hip/hip_runtime.h>
#include <math.h>

#define W 131072
#define FR 63                 // floats per pose3d frame (3*21)
#define FPB 16                // frames per block
#define BLKT 128              // 8 threads per frame, 2 waves
#define NBLOCKS (W / FPB)     // 8192
#define POSE_F 1134           // 18 frames * 63
#define POSE_Q 284            // ceil(1134/4)
#define P2D_Q 168             // 16*42/4
#define LDIR_Q 240            // 16*60/4
#define CAM_Q 24              // 16*6/4
#define SMOOTH_TOT ((W - 1) * FR)

__global__ __launch_bounds__(BLKT) void loss_pass1(
    const float* __restrict__ pose3d,
    const float* __restrict__ cam,
    const float* __restrict__ p2d,
    const float* __restrict__ blen,
    const float* __restrict__ ldir,
    const int* __restrict__ bcon,
    const int* __restrict__ lcon,
    float* __restrict__ partial)
{
  __shared__ float sPose[POSE_Q * 4];     // 1136 floats
  __shared__ float sP2d[P2D_Q * 4];       // 672
  __shared__ float sLdir[LDIR_Q * 4];     // 960
  __shared__ float sCam[CAM_Q * 4];       // 96
  __shared__ int   sBC[40], sLC[40];
  __shared__ float sBlen[20];
  __shared__ float sWave[2];

  const int tid = threadIdx.x;
  const int blk = blockIdx.x;
  const int f0 = blk * FPB;

  // ---- coalesced staging: all inputs -> LDS ----
  {
    const float4* g = (const float4*)(pose3d + (size_t)f0 * FR);  // 16B aligned
    float4* d = (float4*)sPose;
    const int avail = ((W + 1) - f0) * FR;   // floats present (last blk: 1071)
#pragma unroll
    for (int it = 0; it < 3; ++it) {
      int q = tid + it * BLKT;
      if (q < POSE_Q) {
        int j = 4 * q;
        if (j + 4 <= avail) d[q] = g[q];
        else {
          const float* gs = (const float*)g;
#pragma unroll
          for (int k = 0; k < 4; ++k)
            sPose[j + k] = (j + k < avail) ? gs[j + k] : 0.0f;
        }
      }
    }
  }
  {
    const float4* g = (const float4*)(p2d + (size_t)f0 * 42);
    float4* d = (float4*)sP2d;
#pragma unroll
    for (int it = 0; it < 2; ++it) {
      int q = tid + it * BLKT;
      if (q < P2D_Q) d[q] = g[q];
    }
  }
  {
    const float4* g = (const float4*)(ldir + (size_t)f0 * 60);
    float4* d = (float4*)sLdir;
#pragma unroll
    for (int it = 0; it < 2; ++it) {
      int q = tid + it * BLKT;
      if (q < LDIR_Q) d[q] = g[q];
    }
  }
  {
    const float4* g = (const float4*)(cam + (size_t)f0 * 6);
    float4* d = (float4*)sCam;
    if (tid < CAM_Q) d[tid] = g[tid];
  }
  if (tid < 40) { sBC[tid] = bcon[tid]; sLC[tid] = lcon[tid]; }
  else if (tid < 60) sBlen[tid - 40] = blen[tid - 40];
  __syncthreads();

  // ---- smoothness: flat stencil over 16*63=1008 local outputs ----
  float acc_smooth = 0.0f;
  {
    const int n_s_all = FPB * FR;
    const int n_s = (blk == NBLOCKS - 1) ? (SMOOTH_TOT - f0 * FR) : n_s_all;
#pragma unroll
    for (int c = 0; c < 2; ++c) {
      int o = c * 512 + 4 * tid;
#pragma unroll
      for (int e = 0; e < 4; ++e) {
        int oo = o + e;
        if (oo < n_s) {
          float d2 = sPose[oo + 126] - 2.0f * sPose[oo + 63] + sPose[oo];
          acc_smooth += d2 * d2;
        }
      }
    }
  }

  const int s  = tid & 7;
  const int fl = tid >> 3;
  const int w  = f0 + fl;                    // 0..W-1
  const float* P1 = sPose + (fl + 1) * FR;   // frame w+1

  // ---- projection: joints j = s + 8k ----
  float acc_proj = 0.0f;
  {
    const float* cp = sCam + fl * 6;
    float c00 = cp[0], c01 = cp[1], c02 = cp[2];
    float c10 = cp[3], c11 = cp[4], c12 = cp[5];
    const float* pr = sP2d + fl * 42;
#pragma unroll
    for (int k = 0; k < 3; ++k) {
      int j = s + 8 * k;
      if (j < 21) {
        float x = P1[j], y = P1[21 + j], z = P1[42 + j];
        float d0 = c00 * x + c01 * y + c02 * z - pr[j];
        float d1 = c10 * x + c11 * y + c12 * z - pr[21 + j];
        acc_proj += d0 * d0 + d1 * d1;
      }
    }
  }

  // ---- lift + bone: bones b = s + 8k (frame w+1, covers frames 1..W) ----
  float acc_bone = 0.0f, acc_lift = 0.0f;
  {
    const float* lr = sLdir + fl * 60;
#pragma unroll
    for (int k = 0; k < 3; ++k) {
      int b = s + 8 * k;
      if (b < 20) {
        int lcx = sLC[2 * b], lcy = sLC[2 * b + 1];
        float dx = P1[lcx]      - P1[lcy];
        float dy = P1[21 + lcx] - P1[21 + lcy];
        float dz = P1[42 + lcx] - P1[42 + lcy];
        float S = dx * dx + dy * dy + dz * dz;
        float inv = rsqrtf(S);
        float ex = lr[b]      - dx * inv;
        float ey = lr[20 + b] - dy * inv;
        float ez = lr[40 + b] - dz * inv;
        acc_lift += ex * ex + ey * ey + ez * ez;

        int bcx = sBC[2 * b], bcy = sBC[2 * b + 1];
        float Sb = S;
        if (bcx != lcx || bcy != lcy) {      // dataset: execz-skipped
          float bx = P1[bcx]      - P1[bcy];
          float by = P1[21 + bcx] - P1[21 + bcy];
          float bz = P1[42 + bcx] - P1[42 + bcy];
          Sb = bx * bx + by * by + bz * bz;
        }
        float t = Sb - sBlen[b];
        acc_bone += t * t;
      }
    }
    if (w == 0 && fl == 0) {   // frame 0's bone term (block 0, threads 0..7)
      const float* P0 = sPose;
#pragma unroll
      for (int k = 0; k < 3; ++k) {
        int b = s + 8 * k;
        if (b < 20) {
          int bcx = sBC[2 * b], bcy = sBC[2 * b + 1];
          float bx = P0[bcx]      - P0[bcy];
          float by = P0[21 + bcx] - P0[21 + bcy];
          float bz = P0[42 + bcx] - P0[42 + bcy];
          float Sb = bx * bx + by * by + bz * bz;
          float t = Sb - sBlen[b];
          acc_bone += t * t;
        }
      }
    }
  }

  // ---- weighted combine + block reduction (2 waves) ----
  float tot = acc_proj * (1.0f / 42.0f) + acc_bone * (1.0f / 20.0f)
            + acc_smooth * (0.5f / 63.0f) + acc_lift * (0.1f / 63.0f);
#pragma unroll
  for (int off = 32; off > 0; off >>= 1) tot += __shfl_xor(tot, off, 64);
  if ((tid & 63) == 0) sWave[tid >> 6] = tot;
  __syncthreads();
  if (tid == 0) partial[blk] = sWave[0] + sWave[1];
}

__global__ __launch_bounds__(256) void loss_pass2(
    const float* __restrict__ partial, float* __restrict__ out)
{
  __shared__ float sW[4];
  int tid = threadIdx.x;
  float s = 0.0f;
#pragma unroll
  for (int i = 0; i < NBLOCKS / 256; ++i) s += partial[i * 256 + tid];
#pragma unroll
  for (int off = 32; off > 0; off >>= 1) s += __shfl_xor(s, off, 64);
  if ((tid & 63) == 0) sW[tid >> 6] = s;
  __syncthreads();
  if (tid == 0) {
    float t = 0.0f;
#pragma unroll
    for (int i = 0; i < 4; ++i) t += sW[i];
    out[0] = t;
  }
}

extern "C" void kernel_launch(void* const* d_in, const int* in_sizes, int n_in,
                              void* d_out, int out_size, void* d_ws, size_t ws_size,
                              hipStream_t stream) {
  const float* pose3d = (const float*)d_in[0];
  const float* cam    = (const float*)d_in[1];
  const float* p2d    = (const float*)d_in[2];
  const float* blen   = (const float*)d_in[3];
  const float* ldir   = (const float*)d_in[4];
  const int*   bcon   = (const int*)d_in[5];
  const int*   lcon   = (const int*)d_in[6];
  float* out     = (float*)d_out;
  float* partial = (float*)d_ws;   // 8192 floats = 32 KB

  loss_pass1<<<NBLOCKS, BLKT, 0, stream>>>(pose3d, cam, p2d, blen, ldir,
                                           bcon, lcon, partial);
  loss_pass2<<<1, 256, 0, stream>>>(partial, out);
}

// Round 7
// 131.591 us; speedup vs baseline: 1.0003x; 1.0003x over previous
//
#include <hip/hip_runtime.h>
#include <math.h>

#define W 131072
#define FR 63                 // floats per pose3d frame (3*21)
#define FPB 32                // frames per block
#define BLKT 128              // 4 threads per frame, 2 waves
#define NBLOCKS (W / FPB)     // 4096
#define TFR 34                // pose frames staged (fl, fl+1, fl+2 for fl<32)
#define PPITCH 68             // pose LDS pitch (16B-aligned, conflict-free)

__global__ __launch_bounds__(BLKT) void loss_pass1(
    const float* __restrict__ pose3d,
    const float* __restrict__ cam,
    const float* __restrict__ p2d,
    const float* __restrict__ blen,
    const float* __restrict__ ldir,
    const int* __restrict__ bcon,
    const int* __restrict__ lcon,
    float* __restrict__ partial)
{
  __shared__ float sPose[TFR * PPITCH];   // 9248 B
  __shared__ float sP2d[FPB * 42];        // 5376 B
  __shared__ float sLdir[FPB * 60];       // 7680 B
  __shared__ float sCam[FPB * 6];         // 768 B
  __shared__ float sWave[2];

  const int tid = threadIdx.x;
  const int blk = blockIdx.x;
  const int f0 = blk * FPB;

  // ---- pose staging: frame-chunked, pitch-68, ds_write_b128 ----
  {
    const float* src = pose3d + (size_t)f0 * FR;
    const int m = tid & 15;         // float4 slot within frame (covers 0..63)
    const int fi0 = tid >> 4;       // 0..7
    if (blk != NBLOCKS - 1) {
#pragma unroll
      for (int r = 0; r < 5; ++r) {
        int fi = fi0 + 8 * r;
        if (fi < TFR) {
          float4 v = *(const float4*)(src + 63 * fi + 4 * m);  // elem 63 = next frame's 0 (pad, masked later)
          *(float4*)(sPose + PPITCH * fi + 4 * m) = v;
        }
      }
    } else {
      // last block: frames f0..W only (fi 0..32); frame 33 never read
#pragma unroll
      for (int r = 0; r < 5; ++r) {
        int fi = fi0 + 8 * r;
        if (fi <= 32) {
          if (fi < 32 || m < 15) {
            float4 v = *(const float4*)(src + 63 * fi + 4 * m);
            *(float4*)(sPose + PPITCH * fi + 4 * m) = v;
          } else {  // fi==32, m==15: only elements 60..62 exist
            sPose[PPITCH * 32 + 60] = src[63 * 32 + 60];
            sPose[PPITCH * 32 + 61] = src[63 * 32 + 61];
            sPose[PPITCH * 32 + 62] = src[63 * 32 + 62];
          }
        }
      }
    }
  }
  // ---- flat staging: p2d / ldir / cam (exact float4 multiples) ----
  {
    const float4* g = (const float4*)(p2d + (size_t)f0 * 42);
    float4* d = (float4*)sP2d;
#pragma unroll
    for (int it = 0; it < 3; ++it) { int q = tid + it * BLKT; if (q < 336) d[q] = g[q]; }
  }
  {
    const float4* g = (const float4*)(ldir + (size_t)f0 * 60);
    float4* d = (float4*)sLdir;
#pragma unroll
    for (int it = 0; it < 4; ++it) { int q = tid + it * BLKT; if (q < 480) d[q] = g[q]; }
  }
  {
    const float4* g = (const float4*)(cam + (size_t)f0 * 6);
    float4* d = (float4*)sCam;
    if (tid < 48) d[tid] = g[tid];
  }
  __syncthreads();

  const int s  = tid & 3;          // quarter / joint-group / bone-group
  const int fl = tid >> 2;         // local frame 0..31
  const int w  = f0 + fl;          // 0..W-1

  // ---- smoothness: 16-element quarter, 3 taps, ds_read_b128 ----
  float acc_smooth = 0.0f;
  if (w < W - 1) {
    const float* A = sPose + PPITCH * fl + 16 * s;
    const float* B = A + PPITCH;
    const float* C = B + PPITCH;
#pragma unroll
    for (int q = 0; q < 4; ++q) {
      float4 a = *(const float4*)(A + 4 * q);
      float4 b = *(const float4*)(B + 4 * q);
      float4 c = *(const float4*)(C + 4 * q);
      float dx = c.x - 2.0f * b.x + a.x;
      float dy = c.y - 2.0f * b.y + a.y;
      float dz = c.z - 2.0f * b.z + a.z;
      float dw = c.w - 2.0f * b.w + a.w;
      if (q == 3 && s == 3) dw = 0.0f;   // element 63 is pad
      acc_smooth += dx * dx + dy * dy + dz * dz + dw * dw;
    }
  }

  const float* P1 = sPose + PPITCH * (fl + 1);   // frame w+1

  // ---- projection: joints j = 5s+k (s==3 also takes j=20) ----
  float acc_proj = 0.0f;
  {
    const float* cp = sCam + 6 * fl;
    float c00 = cp[0], c01 = cp[1], c02 = cp[2];
    float c10 = cp[3], c11 = cp[4], c12 = cp[5];
    const float* pr = sP2d + 42 * fl;
    const int kend = (s == 3) ? 6 : 5;
#pragma unroll
    for (int k = 0; k < 6; ++k) {
      if (k < kend) {
        int j = 5 * s + k;
        float x = P1[j], y = P1[21 + j], z = P1[42 + j];
        float d0 = c00 * x + c01 * y + c02 * z - pr[j];
        float d1 = c10 * x + c11 * y + c12 * z - pr[21 + j];
        acc_proj += d0 * d0 + d1 * d1;
      }
    }
  }

  // ---- lift + bone: bones b = 5s+k (frame w+1, covers frames 1..W) ----
  float acc_bone = 0.0f, acc_lift = 0.0f;
  {
    const float* lr = sLdir + 60 * fl;
    const int2* bc2 = (const int2*)bcon;
    const int2* lc2 = (const int2*)lcon;
    int2 lcA[5], bcA[5];
    float blA[5];
    bool ch = true;
#pragma unroll
    for (int k = 0; k < 5; ++k) {
      int b = 5 * s + k;
      lcA[k] = lc2[b]; bcA[k] = bc2[b]; blA[k] = blen[b];
      ch = ch && lcA[k].x == b + 1 && lcA[k].y == b
              && bcA[k].x == b + 1 && bcA[k].y == b;
    }
    if (__all(ch)) {
      // kinematic chain: adjacent-pair diffs, bone reuses lift's S
#pragma unroll
      for (int k = 0; k < 5; ++k) {
        int b = 5 * s + k;
        float dx = P1[b + 1]      - P1[b];
        float dy = P1[21 + b + 1] - P1[21 + b];
        float dz = P1[42 + b + 1] - P1[42 + b];
        float S = dx * dx + dy * dy + dz * dz;
        float inv = rsqrtf(S);
        float ex = lr[b]      - dx * inv;
        float ey = lr[20 + b] - dy * inv;
        float ez = lr[40 + b] - dz * inv;
        acc_lift += ex * ex + ey * ey + ez * ez;
        float t = S - blA[k];
        acc_bone += t * t;
      }
    } else {
#pragma unroll
      for (int k = 0; k < 5; ++k) {
        int b = 5 * s + k;
        int2 lc = lcA[k];
        float dx = P1[lc.x]      - P1[lc.y];
        float dy = P1[21 + lc.x] - P1[21 + lc.y];
        float dz = P1[42 + lc.x] - P1[42 + lc.y];
        float S = dx * dx + dy * dy + dz * dz;
        float inv = rsqrtf(S);
        float ex = lr[b]      - dx * inv;
        float ey = lr[20 + b] - dy * inv;
        float ez = lr[40 + b] - dz * inv;
        acc_lift += ex * ex + ey * ey + ez * ez;
        int2 bc = bcA[k];
        float Sb = S;
        if (bc.x != lc.x || bc.y != lc.y) {
          float bx = P1[bc.x]      - P1[bc.y];
          float by = P1[21 + bc.x] - P1[21 + bc.y];
          float bz = P1[42 + bc.x] - P1[42 + bc.y];
          Sb = bx * bx + by * by + bz * bz;
        }
        float t = Sb - blA[k];
        acc_bone += t * t;
      }
    }
    if (blk == 0 && fl == 0) {   // frame 0's bone term (threads 0..3)
      const float* P0 = sPose;
#pragma unroll
      for (int k = 0; k < 5; ++k) {
        int2 bc = bcA[k];
        float bx = P0[bc.x]      - P0[bc.y];
        float by = P0[21 + bc.x] - P0[21 + bc.y];
        float bz = P0[42 + bc.x] - P0[42 + bc.y];
        float Sb = bx * bx + by * by + bz * bz;
        float t = Sb - blA[k];
        acc_bone += t * t;
      }
    }
  }

  // ---- weighted combine + block reduction (2 waves) ----
  float tot = acc_proj * (1.0f / 42.0f) + acc_bone * (1.0f / 20.0f)
            + acc_smooth * (0.5f / 63.0f) + acc_lift * (0.1f / 63.0f);
#pragma unroll
  for (int off = 32; off > 0; off >>= 1) tot += __shfl_xor(tot, off, 64);
  if ((tid & 63) == 0) sWave[tid >> 6] = tot;
  __syncthreads();
  if (tid == 0) partial[blk] = sWave[0] + sWave[1];
}

__global__ __launch_bounds__(256) void loss_pass2(
    const float* __restrict__ partial, float* __restrict__ out)
{
  __shared__ float sW[4];
  int tid = threadIdx.x;
  float s = 0.0f;
#pragma unroll
  for (int i = 0; i < NBLOCKS / 256; ++i) s += partial[i * 256 + tid];
#pragma unroll
  for (int off = 32; off > 0; off >>= 1) s += __shfl_xor(s, off, 64);
  if ((tid & 63) == 0) sW[tid >> 6] = s;
  __syncthreads();
  if (tid == 0) {
    float t = 0.0f;
#pragma unroll
    for (int i = 0; i < 4; ++i) t += sW[i];
    out[0] = t;
  }
}

extern "C" void kernel_launch(void* const* d_in, const int* in_sizes, int n_in,
                              void* d_out, int out_size, void* d_ws, size_t ws_size,
                              hipStream_t stream) {
  const float* pose3d = (const float*)d_in[0];
  const float* cam    = (const float*)d_in[1];
  const float* p2d    = (const float*)d_in[2];
  const float* blen   = (const float*)d_in[3];
  const float* ldir   = (const float*)d_in[4];
  const int*   bcon   = (const int*)d_in[5];
  const int*   lcon   = (const int*)d_in[6];
  float* out     = (float*)d_out;
  float* partial = (float*)d_ws;   // 4096 floats = 16 KB

  loss_pass1<<<NBLOCKS, BLKT, 0, stream>>>(pose3d, cam, p2d, blen, ldir,
                                           bcon, lcon, partial);
  loss_pass2<<<1, 256, 0, stream>>>(partial, out);
}

// Round 8
// 127.951 us; speedup vs baseline: 1.0287x; 1.0285x over previous
//
#include <hip/hip_runtime.h>
#include <math.h>

#define W 131072
#define FR 63                 // floats per pose3d frame (3*21)
#define FPB 32                // frames per block
#define BLKT 256              // 4 waves
#define NBLOCKS (W / FPB)     // 4096
#define SMOOTH_TOT ((W - 1) * FR)

__global__ __launch_bounds__(BLKT, 8) void loss_pass1(
    const float* __restrict__ pose3d,
    const float* __restrict__ cam,
    const float* __restrict__ p2d,
    const float* __restrict__ blen,
    const float* __restrict__ ldir,
    const int* __restrict__ bcon,
    const int* __restrict__ lcon,
    float* __restrict__ partial)
{
  __shared__ float sCam[FPB * 6];   // 768 B
  __shared__ float sBlen[20];
  __shared__ int   sBC[40], sLC[40];
  __shared__ float sWave[4];

  const int tid = threadIdx.x;
  const int blk = blockIdx.x;
  const int f0 = blk * FPB;
  const float* src = pose3d + (size_t)f0 * FR;   // flat base of frame f0

  // ---- tiny staging: cam tile + bone tables + lengths ----
  {
    if (tid < 48) ((float4*)sCam)[tid] = ((const float4*)(cam + (size_t)f0 * 6))[tid];
    if (tid >= 64 && tid < 104) { int i = tid - 64; sBC[i] = bcon[i]; sLC[i] = lcon[i]; }
    if (tid >= 128 && tid < 148) sBlen[tid - 128] = blen[tid - 128];
  }
  __syncthreads();

  float acc_smooth = 0.0f, acc_proj = 0.0f, acc_bone = 0.0f, acc_lift = 0.0f;

  // ---- smooth: flat coalesced 3-tap stencil, 2016 outputs/block ----
  {
    const int lim = (blk == NBLOCKS - 1) ? (SMOOTH_TOT - f0 * FR) : (FPB * FR);
#pragma unroll
    for (int k = 0; k < 8; ++k) {
      int o = k * BLKT + tid;
      if (o < lim) {
        float d2 = src[o + 126] - 2.0f * src[o + 63] + src[o];
        acc_smooth += d2 * d2;
      }
    }
  }

  // ---- projection: task (f, j), 672 per block ----
#pragma unroll
  for (int k = 0; k < 3; ++k) {
    int t = k * BLKT + tid;
    if (t < FPB * 21) {
      int f = t / 21;
      int j = t - 21 * f;
      const float* P1 = src + (f + 1) * FR;   // frame w+1, L1-hot
      float x = P1[j], y = P1[21 + j], z = P1[42 + j];
      const float* cp = sCam + 6 * f;
      const float* pr = p2d + (size_t)(f0 + f) * 42;
      float d0 = cp[0] * x + cp[1] * y + cp[2] * z - pr[j];
      float d1 = cp[3] * x + cp[4] * y + cp[5] * z - pr[21 + j];
      acc_proj += d0 * d0 + d1 * d1;
    }
  }

  // ---- lift + bone: task (f, b), 640 per block; covers bone frames 1..W ----
#pragma unroll
  for (int k = 0; k < 3; ++k) {
    int t = k * BLKT + tid;
    if (t < FPB * 20) {
      int f = t / 20;
      int b = t - 20 * f;
      const float* P1 = src + (f + 1) * FR;
      int lcx = sLC[2 * b], lcy = sLC[2 * b + 1];
      float dx = P1[lcx]      - P1[lcy];
      float dy = P1[21 + lcx] - P1[21 + lcy];
      float dz = P1[42 + lcx] - P1[42 + lcy];
      float S = dx * dx + dy * dy + dz * dz;
      float inv = rsqrtf(S);
      const float* lr = ldir + (size_t)(f0 + f) * 60;
      float ex = lr[b]      - dx * inv;
      float ey = lr[20 + b] - dy * inv;
      float ez = lr[40 + b] - dz * inv;
      acc_lift += ex * ex + ey * ey + ez * ez;

      int bcx = sBC[2 * b], bcy = sBC[2 * b + 1];
      float Sb = S;
      if (bcx != lcx || bcy != lcy) {   // dataset: identical tables -> execz skip
        float bx = P1[bcx]      - P1[bcy];
        float by = P1[21 + bcx] - P1[21 + bcy];
        float bz = P1[42 + bcx] - P1[42 + bcy];
        Sb = bx * bx + by * by + bz * bz;
      }
      float tt = Sb - sBlen[b];
      acc_bone += tt * tt;

      if (blk == 0 && t < 20) {   // frame 0's bone term (f==0 -> t==b)
        float bx = src[bcx]      - src[bcy];
        float by = src[21 + bcx] - src[21 + bcy];
        float bz = src[42 + bcx] - src[42 + bcy];
        float S0 = bx * bx + by * by + bz * bz;
        float t0 = S0 - sBlen[b];
        acc_bone += t0 * t0;
      }
    }
  }

  // ---- weighted combine + block reduction (4 waves) ----
  float tot = acc_proj * (1.0f / 42.0f) + acc_bone * (1.0f / 20.0f)
            + acc_smooth * (0.5f / 63.0f) + acc_lift * (0.1f / 63.0f);
#pragma unroll
  for (int off = 32; off > 0; off >>= 1) tot += __shfl_xor(tot, off, 64);
  if ((tid & 63) == 0) sWave[tid >> 6] = tot;
  __syncthreads();
  if (tid == 0) partial[blk] = (sWave[0] + sWave[1]) + (sWave[2] + sWave[3]);
}

__global__ __launch_bounds__(256) void loss_pass2(
    const float* __restrict__ partial, float* __restrict__ out)
{
  __shared__ float sW[4];
  int tid = threadIdx.x;
  float s = 0.0f;
#pragma unroll
  for (int i = 0; i < NBLOCKS / 256; ++i) s += partial[i * 256 + tid];
#pragma unroll
  for (int off = 32; off > 0; off >>= 1) s += __shfl_xor(s, off, 64);
  if ((tid & 63) == 0) sW[tid >> 6] = s;
  __syncthreads();
  if (tid == 0) {
    float t = 0.0f;
#pragma unroll
    for (int i = 0; i < 4; ++i) t += sW[i];
    out[0] = t;
  }
}

extern "C" void kernel_launch(void* const* d_in, const int* in_sizes, int n_in,
                              void* d_out, int out_size, void* d_ws, size_t ws_size,
                              hipStream_t stream) {
  const float* pose3d = (const float*)d_in[0];
  const float* cam    = (const float*)d_in[1];
  const float* p2d    = (const float*)d_in[2];
  const float* blen   = (const float*)d_in[3];
  const float* ldir   = (const float*)d_in[4];
  const int*   bcon   = (const int*)d_in[5];
  const int*   lcon   = (const int*)d_in[6];
  float* out     = (float*)d_out;
  float* partial = (float*)d_ws;   // 4096 floats = 16 KB

  loss_pass1<<<NBLOCKS, BLKT, 0, stream>>>(pose3d, cam, p2d, blen, ldir,
                                           bcon, lcon, partial);
  loss_pass2<<<1, 256, 0, stream>>>(partial, out);
}

// Round 9
// 121.860 us; speedup vs baseline: 1.0802x; 1.0500x over previous
//
#include <hip/hip_runtime.h>
#include <math.h>

#define W 131072
#define FR 63                 // floats per pose3d frame (3*21)
#define FPB 32                // frames per block
#define BLKT 256              // 4 waves
#define NBLOCKS (W / FPB)     // 4096
#define STG4 536              // float4 slots staged (2144 floats >= 34 frames)
#define POSE_LAST 2079        // floats available in last block (33 frames)
#define SMOOTH_TOT ((W - 1) * FR)

__global__ __launch_bounds__(BLKT, 6) void loss_pass1(
    const float* __restrict__ pose3d,
    const float* __restrict__ cam,
    const float* __restrict__ p2d,
    const float* __restrict__ blen,
    const float* __restrict__ ldir,
    const int* __restrict__ bcon,
    const int* __restrict__ lcon,
    float* __restrict__ partial)
{
  __shared__ float sP[STG4 * 4];   // 8576 B
  __shared__ float sBlen[20];
  __shared__ int   sBC[40], sLC[40];
  __shared__ float sWave[4];

  const int tid = threadIdx.x;
  const int blk = blockIdx.x;
  const int f0 = blk * FPB;
  const float* src = pose3d + (size_t)f0 * FR;

  // ---- stage pose tile (34 frames) once, aligned float4 -> b128 ----
  {
    const float4* g4 = (const float4*)src;
    float4* s4 = (float4*)sP;
    if (blk != NBLOCKS - 1) {
#pragma unroll
      for (int it = 0; it < 3; ++it) {
        int q = tid + it * BLKT;
        if (q < STG4) s4[q] = g4[q];   // safe: >=35 frames remain for all non-last blocks
      }
    } else {
#pragma unroll
      for (int it = 0; it < 3; ++it) {
        int q = tid + it * BLKT;
        if (q < STG4) {
          int j = 4 * q;
          if (j + 4 <= POSE_LAST) s4[q] = g4[q];
          else {
#pragma unroll
            for (int k = 0; k < 4; ++k)
              sP[j + k] = (j + k < POSE_LAST) ? src[j + k] : 0.0f;
          }
        }
      }
    }
  }
  if (tid < 40) { sBC[tid] = bcon[tid]; sLC[tid] = lcon[tid]; }
  else if (tid < 60) sBlen[tid - 40] = blen[tid - 40];
  __syncthreads();

  float acc_smooth = 0.0f, acc_proj = 0.0f, acc_bone = 0.0f, acc_lift = 0.0f;

  // ---- smooth: conflict-free stride-1 LDS stencil, 2016 outputs/block ----
  {
    const int lim = (blk == NBLOCKS - 1) ? (SMOOTH_TOT - f0 * FR) : (FPB * FR);
#pragma unroll
    for (int k = 0; k < 8; ++k) {
      int o = tid + k * BLKT;
      if (o < lim) {
        float d2 = sP[o + 126] - 2.0f * sP[o + 63] + sP[o];
        acc_smooth += d2 * d2;
      }
    }
  }

  // ---- projection: task (f, j), 672/block; pose from LDS, p2d/cam global ----
#pragma unroll
  for (int k = 0; k < 3; ++k) {
    int t = tid + k * BLKT;
    if (t < FPB * 21) {
      int f = t / 21;
      int j = t - 21 * f;
      const float* P1 = sP + FR * (f + 1);
      float x = P1[j], y = P1[21 + j], z = P1[42 + j];
      const float* cp = cam + (size_t)(f0 + f) * 6;
      const float* pr = p2d + (size_t)(f0 + f) * 42;
      float d0 = cp[0] * x + cp[1] * y + cp[2] * z - pr[j];
      float d1 = cp[3] * x + cp[4] * y + cp[5] * z - pr[21 + j];
      acc_proj += d0 * d0 + d1 * d1;
    }
  }

  // ---- lift + bone: task (f, b), 640/block; covers bone frames 1..W ----
#pragma unroll
  for (int k = 0; k < 3; ++k) {
    int t = tid + k * BLKT;
    if (t < FPB * 20) {
      int f = t / 20;
      int b = t - 20 * f;
      const float* P1 = sP + FR * (f + 1);
      int lcx = sLC[2 * b], lcy = sLC[2 * b + 1];
      float dx = P1[lcx]      - P1[lcy];
      float dy = P1[21 + lcx] - P1[21 + lcy];
      float dz = P1[42 + lcx] - P1[42 + lcy];
      float S = dx * dx + dy * dy + dz * dz;
      float inv = rsqrtf(S);
      const float* lr = ldir + (size_t)(f0 + f) * 60;
      float ex = lr[b]      - dx * inv;
      float ey = lr[20 + b] - dy * inv;
      float ez = lr[40 + b] - dz * inv;
      acc_lift += ex * ex + ey * ey + ez * ez;

      int bcx = sBC[2 * b], bcy = sBC[2 * b + 1];
      float Sb = S;
      if (bcx != lcx || bcy != lcy) {   // dataset: identical tables -> execz skip
        float bx = P1[bcx]      - P1[bcy];
        float by = P1[21 + bcx] - P1[21 + bcy];
        float bz = P1[42 + bcx] - P1[42 + bcy];
        Sb = bx * bx + by * by + bz * bz;
      }
      float tt = Sb - sBlen[b];
      acc_bone += tt * tt;

      if (blk == 0 && t < 20) {   // frame 0's bone term (f==0 -> t==b)
        float bx = sP[bcx]      - sP[bcy];
        float by = sP[21 + bcx] - sP[21 + bcy];
        float bz = sP[42 + bcx] - sP[42 + bcy];
        float S0 = bx * bx + by * by + bz * bz;
        float t0 = S0 - sBlen[b];
        acc_bone += t0 * t0;
      }
    }
  }

  // ---- weighted combine + block reduction (4 waves) ----
  float tot = acc_proj * (1.0f / 42.0f) + acc_bone * (1.0f / 20.0f)
            + acc_smooth * (0.5f / 63.0f) + acc_lift * (0.1f / 63.0f);
#pragma unroll
  for (int off = 32; off > 0; off >>= 1) tot += __shfl_xor(tot, off, 64);
  if ((tid & 63) == 0) sWave[tid >> 6] = tot;
  __syncthreads();
  if (tid == 0) partial[blk] = (sWave[0] + sWave[1]) + (sWave[2] + sWave[3]);
}

__global__ __launch_bounds__(256) void loss_pass2(
    const float* __restrict__ partial, float* __restrict__ out)
{
  __shared__ float sW[4];
  int tid = threadIdx.x;
  float s = 0.0f;
#pragma unroll
  for (int i = 0; i < NBLOCKS / 256; ++i) s += partial[i * 256 + tid];
#pragma unroll
  for (int off = 32; off > 0; off >>= 1) s += __shfl_xor(s, off, 64);
  if ((tid & 63) == 0) sW[tid >> 6] = s;
  __syncthreads();
  if (tid == 0) {
    float t = 0.0f;
#pragma unroll
    for (int i = 0; i < 4; ++i) t += sW[i];
    out[0] = t;
  }
}

extern "C" void kernel_launch(void* const* d_in, const int* in_sizes, int n_in,
                              void* d_out, int out_size, void* d_ws, size_t ws_size,
                              hipStream_t stream) {
  const float* pose3d = (const float*)d_in[0];
  const float* cam    = (const float*)d_in[1];
  const float* p2d    = (const float*)d_in[2];
  const float* blen   = (const float*)d_in[3];
  const float* ldir   = (const float*)d_in[4];
  const int*   bcon   = (const int*)d_in[5];
  const int*   lcon   = (const int*)d_in[6];
  float* out     = (float*)d_out;
  float* partial = (float*)d_ws;   // 4096 floats = 16 KB

  loss_pass1<<<NBLOCKS, BLKT, 0, stream>>>(pose3d, cam, p2d, blen, ldir,
                                           bcon, lcon, partial);
  loss_pass2<<<1, 256, 0, stream>>>(partial, out);
}

// Round 10
// 120.267 us; speedup vs baseline: 1.0945x; 1.0132x over previous
//
#include <hip/hip_runtime.h>
#include <math.h>

#define W 131072
#define FR 63                 // floats per pose3d frame (3*21)
#define FPB 32                // frames per block
#define BLKT 256              // 4 waves
#define NBLOCKS (W / FPB)     // 4096
#define STG4 536              // float4 slots staged (2144 floats >= 34 frames)
#define POSE_LAST 2079        // floats available in last block (33 frames)
#define SMOOTH_TOT ((W - 1) * FR)

__global__ __launch_bounds__(BLKT, 6) void loss_pass1(
    const float* __restrict__ pose3d,
    const float* __restrict__ cam,
    const float* __restrict__ p2d,
    const float* __restrict__ blen,
    const float* __restrict__ ldir,
    const int* __restrict__ bcon,
    const int* __restrict__ lcon,
    float* __restrict__ partial)
{
  __shared__ float sP[STG4 * 4];   // 8576 B
  __shared__ float sCam[FPB * 6];  // 768 B
  __shared__ float sBlen[20];
  __shared__ int   sBC[40], sLC[40];
  __shared__ float sWave[4];

  const int tid = threadIdx.x;
  const int blk = blockIdx.x;
  const int f0 = blk * FPB;
  const float* src = pose3d + (size_t)f0 * FR;

  // ---- prefetch ALL single-use global operands into registers (pre-barrier) ----
  int   jp[3]; bool vp[3]; float pd_a[3], pd_b[3];   // proj: p2d pair
  int   fpz[3];
  int   bb[3]; bool vb[3]; float lda[3], ldb[3], ldc[3];  // lift: ldir triple
  int   fbz[3];
#pragma unroll
  for (int k = 0; k < 3; ++k) {
    int t = tid + k * BLKT;
    vp[k] = (t < FPB * 21);
    int tt = vp[k] ? t : 0;
    int f = tt / 21, j = tt - 21 * f;
    fpz[k] = f; jp[k] = j;
    const float* pr = p2d + (size_t)(f0 + f) * 42;
    pd_a[k] = pr[j];
    pd_b[k] = pr[21 + j];

    vb[k] = (t < FPB * 20);
    int tb = vb[k] ? t : 0;
    int f2 = tb / 20, b = tb - 20 * f2;
    fbz[k] = f2; bb[k] = b;
    const float* lr = ldir + (size_t)(f0 + f2) * 60;
    lda[k] = lr[b]; ldb[k] = lr[20 + b]; ldc[k] = lr[40 + b];
  }

  // ---- stage pose tile (34 frames) once, aligned float4 -> b128 ----
  {
    const float4* g4 = (const float4*)src;
    float4* s4 = (float4*)sP;
    if (blk != NBLOCKS - 1) {
#pragma unroll
      for (int it = 0; it < 3; ++it) {
        int q = tid + it * BLKT;
        if (q < STG4) s4[q] = g4[q];
      }
    } else {
#pragma unroll
      for (int it = 0; it < 3; ++it) {
        int q = tid + it * BLKT;
        if (q < STG4) {
          int j = 4 * q;
          if (j + 4 <= POSE_LAST) s4[q] = g4[q];
          else {
#pragma unroll
            for (int k = 0; k < 4; ++k)
              sP[j + k] = (j + k < POSE_LAST) ? src[j + k] : 0.0f;
          }
        }
      }
    }
  }
  // cam tile + tables (pre-barrier)
  if (tid < 48) ((float4*)sCam)[tid] = ((const float4*)(cam + (size_t)f0 * 6))[tid];
  if (tid >= 64 && tid < 104) { int i = tid - 64; sBC[i] = bcon[i]; sLC[i] = lcon[i]; }
  if (tid >= 128 && tid < 148) sBlen[tid - 128] = blen[tid - 128];
  __syncthreads();

  float acc_smooth = 0.0f, acc_proj = 0.0f, acc_bone = 0.0f, acc_lift = 0.0f;

  // ---- smooth: conflict-free stride-1 LDS stencil, 2016 outputs/block ----
  {
    const int lim = (blk == NBLOCKS - 1) ? (SMOOTH_TOT - f0 * FR) : (FPB * FR);
#pragma unroll
    for (int k = 0; k < 8; ++k) {
      int o = tid + k * BLKT;
      if (o < lim) {
        float d2 = sP[o + 126] - 2.0f * sP[o + 63] + sP[o];
        acc_smooth += d2 * d2;
      }
    }
  }

  // ---- projection: consume prefetched p2d; pose + cam from LDS ----
#pragma unroll
  for (int k = 0; k < 3; ++k) {
    if (vp[k]) {
      int f = fpz[k], j = jp[k];
      const float* P1 = sP + FR * (f + 1);
      float x = P1[j], y = P1[21 + j], z = P1[42 + j];
      const float* cp = sCam + 6 * f;
      float d0 = cp[0] * x + cp[1] * y + cp[2] * z - pd_a[k];
      float d1 = cp[3] * x + cp[4] * y + cp[5] * z - pd_b[k];
      acc_proj += d0 * d0 + d1 * d1;
    }
  }

  // ---- lift + bone: consume prefetched ldir; pose + tables from LDS ----
#pragma unroll
  for (int k = 0; k < 3; ++k) {
    if (vb[k]) {
      int f = fbz[k], b = bb[k];
      const float* P1 = sP + FR * (f + 1);
      int lcx = sLC[2 * b], lcy = sLC[2 * b + 1];
      float dx = P1[lcx]      - P1[lcy];
      float dy = P1[21 + lcx] - P1[21 + lcy];
      float dz = P1[42 + lcx] - P1[42 + lcy];
      float S = dx * dx + dy * dy + dz * dz;
      float inv = rsqrtf(S);
      float ex = lda[k] - dx * inv;
      float ey = ldb[k] - dy * inv;
      float ez = ldc[k] - dz * inv;
      acc_lift += ex * ex + ey * ey + ez * ez;

      int bcx = sBC[2 * b], bcy = sBC[2 * b + 1];
      float Sb = S;
      if (bcx != lcx || bcy != lcy) {   // dataset: identical tables -> execz skip
        float bx = P1[bcx]      - P1[bcy];
        float by = P1[21 + bcx] - P1[21 + bcy];
        float bz = P1[42 + bcx] - P1[42 + bcy];
        Sb = bx * bx + by * by + bz * bz;
      }
      float tt = Sb - sBlen[b];
      acc_bone += tt * tt;

      if (blk == 0 && k == 0 && tid < 20) {   // frame 0's bone term (t==b)
        float bx = sP[bcx]      - sP[bcy];
        float by = sP[21 + bcx] - sP[21 + bcy];
        float bz = sP[42 + bcx] - sP[42 + bcy];
        float S0 = bx * bx + by * by + bz * bz;
        float t0 = S0 - sBlen[b];
        acc_bone += t0 * t0;
      }
    }
  }

  // ---- weighted combine + block reduction (4 waves) ----
  float tot = acc_proj * (1.0f / 42.0f) + acc_bone * (1.0f / 20.0f)
            + acc_smooth * (0.5f / 63.0f) + acc_lift * (0.1f / 63.0f);
#pragma unroll
  for (int off = 32; off > 0; off >>= 1) tot += __shfl_xor(tot, off, 64);
  if ((tid & 63) == 0) sWave[tid >> 6] = tot;
  __syncthreads();
  if (tid == 0) partial[blk] = (sWave[0] + sWave[1]) + (sWave[2] + sWave[3]);
}

__global__ __launch_bounds__(256) void loss_pass2(
    const float* __restrict__ partial, float* __restrict__ out)
{
  __shared__ float sW[4];
  int tid = threadIdx.x;
  float s = 0.0f;
#pragma unroll
  for (int i = 0; i < NBLOCKS / 256; ++i) s += partial[i * 256 + tid];
#pragma unroll
  for (int off = 32; off > 0; off >>= 1) s += __shfl_xor(s, off, 64);
  if ((tid & 63) == 0) sW[tid >> 6] = s;
  __syncthreads();
  if (tid == 0) {
    float t = 0.0f;
#pragma unroll
    for (int i = 0; i < 4; ++i) t += sW[i];
    out[0] = t;
  }
}

extern "C" void kernel_launch(void* const* d_in, const int* in_sizes, int n_in,
                              void* d_out, int out_size, void* d_ws, size_t ws_size,
                              hipStream_t stream) {
  const float* pose3d = (const float*)d_in[0];
  const float* cam    = (const float*)d_in[1];
  const float* p2d    = (const float*)d_in[2];
  const float* blen   = (const float*)d_in[3];
  const float* ldir   = (const float*)d_in[4];
  const int*   bcon   = (const int*)d_in[5];
  const int*   lcon   = (const int*)d_in[6];
  float* out     = (float*)d_out;
  float* partial = (float*)d_ws;   // 4096 floats = 16 KB

  loss_pass1<<<NBLOCKS, BLKT, 0, stream>>>(pose3d, cam, p2d, blen, ldir,
                                           bcon, lcon, partial);
  loss_pass2<<<1, 256, 0, stream>>>(partial, out);
}